// Round 1
// baseline (171.964 us; speedup 1.0000x reference)
//
#include <hip/hip_runtime.h>
#include <math.h>

#define Nn 65536

typedef short s16x8 __attribute__((ext_vector_type(8)));
typedef float f32x4 __attribute__((ext_vector_type(4)));
typedef unsigned int u32;

__device__ __forceinline__ unsigned short f2bf(float x) {
    u32 u = __float_as_uint(x);
    u += 0x7FFFu + ((u >> 16) & 1u);
    return (unsigned short)(u >> 16);
}

// argmax over row s of the 4x4 type_matching (first max wins, matches jnp.argmax)
__device__ __forceinline__ int best_t_for(const float* __restrict__ tm, int s, float* mOut) {
    float m = tm[s * 4];
    int am = 0;
#pragma unroll
    for (int j = 1; j < 4; ++j) {
        float v = tm[s * 4 + j];
        if (v > m) { m = v; am = j; }
    }
    if (mOut) *mOut = m;
    return am;
}

// ============ k_prep ============
// blocks 0..255   : partition (1 item/thread, ballot-prefix positions, poison-CAS global reserve)
// blocks 256..447 : weight convert fp32 [D][H] -> bf16 fragment-linear (half-fragment per thread)
__global__ void k_prep(const int* __restrict__ type_ids, const float* __restrict__ tm,
                       const float* __restrict__ W1, const float* __restrict__ W2,
                       const float* __restrict__ C1,
                       int* __restrict__ counts, int* __restrict__ buckets,
                       unsigned short* __restrict__ wbf, float* __restrict__ out_prob) {
    const int tid = threadIdx.x;
    if (blockIdx.x < 256) {
        __shared__ float prob[4];
        __shared__ int waveCnt[4][4];   // [wave][type]
        __shared__ int waveBase[4][4];
        if (tid < 4) {
            float m;
            best_t_for(tm, tid, &m);
            prob[tid] = 1.f / (1.f + expf(-m));
        }
        __syncthreads();
        const int gid = blockIdx.x * 256 + tid;
        const int id = type_ids[gid];
        out_prob[gid] = prob[id];
        const int lane = tid & 63;
        const int wv = tid >> 6;
        const unsigned long long lt = (1ull << lane) - 1ull;
        int myPrefix = 0;
#pragma unroll
        for (int sv = 0; sv < 4; ++sv) {
            unsigned long long m = __ballot(id == sv);
            if (id == sv) myPrefix = (int)__popcll(m & lt);
            if (lane == 0) waveCnt[wv][sv] = (int)__popcll(m);
        }
        __syncthreads();
        if (tid < 4) {
            const int sv = tid;
            int c0 = waveCnt[0][sv], c1 = waveCnt[1][sv];
            int c2_ = waveCnt[2][sv], c3 = waveCnt[3][sv];
            int tot = c0 + c1 + c2_ + c3;
            // poison-CAS reservation: no memset node needed (counts harness-poisoned 0xAAAAAAAA)
            u32 old = atomicCAS((u32*)&counts[sv], 0xAAAAAAAAu, (u32)tot);
            int base = (old == 0xAAAAAAAAu) ? 0 : atomicAdd(&counts[sv], tot);
            waveBase[0][sv] = base;
            waveBase[1][sv] = base + c0;
            waveBase[2][sv] = base + c0 + c1;
            waveBase[3][sv] = base + c0 + c1 + c2_;
        }
        __syncthreads();
        buckets[id * Nn + waveBase[wv][id] + myPrefix] = gid;
    } else {
        // weight convert: 12 live matrices, 2048 fragments each, 2 threads per fragment
        int v = (blockIdx.x - 256) * 256 + tid;   // 0..49151
        int f_lin = v >> 1;                       // fragment index 0..24575
        int half = v & 1;
        int mat = f_lin >> 11;
        int rr = f_lin & 2047;
        int f = rr >> 6, lane = rr & 63;
        int kk = f >> 3, n8 = f & 7;
        int q = lane >> 4, l15 = lane & 15;
        int sm = mat / 3, w = mat - sm * 3;
        int t = best_t_for(tm, sm, nullptr);
        const float* src = (w == 0) ? W1 : (w == 1) ? W2 : C1;
        const float* sp = src + (((sm * 4 + t) << 14) + n8 * 16 + l15);
        int k0 = kk * 32 + q * 8 + half * 4;
        ushort4 o;
        o.x = f2bf(sp[(k0 + 0) * 128]);
        o.y = f2bf(sp[(k0 + 1) * 128]);
        o.z = f2bf(sp[(k0 + 2) * 128]);
        o.w = f2bf(sp[(k0 + 3) * 128]);
        *(ushort4*)(wbf + (size_t)f_lin * 8 + half * 4) = o;
    }
}

// ================= k_main =================
// Single-buffered A, 1 tile per block (grid 288x4 covers ntiles~256; strided loop only for
// pathological type imbalance). Weights loaded per-phase from L2-resident wbf into 2
// alternating 32-reg fragment sets -> combined VGPR+AGPR fits __launch_bounds__(256,3)
// (3 blocks/CU, 12 waves/CU; the old register-held wf[3][4][2]=96 regs forced 2 blocks/CU).
// A/H layout: row*128 + ((col + (row&15)*8) & 127) -- pad-free, conflict-free b128 frags
__global__ __launch_bounds__(256, 3) void k_main(
    const float* __restrict__ states, const float* __restrict__ scores,
    const float* __restrict__ b1g, const float* __restrict__ b2g, const float* __restrict__ c1g,
    const float* __restrict__ tm, const float* __restrict__ C2, const float* __restrict__ c2,
    const int* __restrict__ counts, const int* __restrict__ buckets,
    const unsigned short* __restrict__ wbf,
    float* __restrict__ out_state, float* __restrict__ out_score)
{
    __shared__ __align__(16) unsigned short Abuf[64 * 128];   // 16 KB
    __shared__ __align__(16) unsigned short Hbuf[64 * 128];   // 16 KB
    __shared__ int gIdxLds[64];
    __shared__ float scoreLds[64];
    __shared__ float pLds[4][64];
    __shared__ float C2s[128];

    const int s = blockIdx.y;
    const int cnt = counts[s];
    const int ntiles = (cnt + 63) >> 6;
    if ((int)blockIdx.x >= ntiles) return;
    const int t = threadIdx.x;
    const int tt = best_t_for(tm, s, nullptr);
    const int stIdx = s * 4 + tt;

    const int lane = t & 63;
    const int wv = t >> 6;           // wave -> 32-col slice (n-groups 2wv, 2wv+1)
    const int l15 = lane & 15;
    const int quad = lane >> 4;
    const int myRow = t >> 2;        // A staging: 4 threads per row
    const int q4 = t & 3;

    if (t >= 128) C2s[t - 128] = C2[stIdx * 128 + (t - 128)];

    // hoisted per-lane bias/weight constants
    float b1v[2], b2v[2], c1v[2];
#pragma unroll
    for (int nn = 0; nn < 2; ++nn) {
        int col = (wv * 2 + nn) * 16 + l15;
        b1v[nn] = b1g[stIdx * 128 + col];
        b2v[nn] = b2g[stIdx * 128 + col];
        c1v[nn] = c1g[stIdx * 128 + col];
    }
    const float c2s = c2[stIdx];
    const int* bkt = buckets + s * Nn;
    const unsigned short* wb = wbf + (size_t)s * 3 * 16384;

    // load one matrix's fragments for this wave's col-slice (32 VGPRs, from L2-resident wbf)
    auto loadW = [&](int m, s16x8 wf[4][2]) {
#pragma unroll
        for (int kk = 0; kk < 4; ++kk)
#pragma unroll
            for (int nn = 0; nn < 2; ++nn)
                wf[kk][nn] = *(const s16x8*)(wb + m * 16384 +
                    (size_t)((kk * 8 + (wv * 2 + nn)) * 64 + lane) * 8);
    };

    // gemm: A-frags from swizzled LDS, B-frags from registers
    auto gemm = [&](const unsigned short* Ab, const s16x8 wf[4][2], f32x4 acc[4][2]) {
#pragma unroll
        for (int mg = 0; mg < 4; ++mg)
#pragma unroll
            for (int nn = 0; nn < 2; ++nn) acc[mg][nn] = f32x4{0.f, 0.f, 0.f, 0.f};
#pragma unroll
        for (int kk = 0; kk < 4; ++kk) {
            const int colsw = (kk * 32 + quad * 8 + l15 * 8) & 127;  // row&15 == l15
            s16x8 af[4];
#pragma unroll
            for (int mg = 0; mg < 4; ++mg)
                af[mg] = *(const s16x8*)(Ab + (mg * 16 + l15) * 128 + colsw);
#pragma unroll
            for (int mg = 0; mg < 4; ++mg)
#pragma unroll
                for (int nn = 0; nn < 2; ++nn)
                    acc[mg][nn] = __builtin_amdgcn_mfma_f32_16x16x32_bf16(
                        af[mg], wf[kk][nn], acc[mg][nn], 0, 0, 0);
        }
    };

    s16x8 wfX[4][2], wfY[4][2];
    f32x4 acc[4][2];

    for (int tile = blockIdx.x; tile < ntiles; tile += gridDim.x) {
        loadW(0, wfX);                       // W1 (L2 loads overlap A-stage HBM loads)

        // ---- stage tile's A rows -> swizzled bf16 LDS ----
        {
            int gr = tile * 64 + myRow;
            int g = (gr < cnt) ? bkt[gr] : -1;
            if (q4 == 0) {
                gIdxLds[myRow] = g;
                scoreLds[myRow] = (g >= 0) ? scores[g] : 0.f;
            }
            unsigned short* dstRow = &Abuf[myRow * 128];
            const int rot = (myRow & 15) << 3;
            if (g >= 0) {
                const float4* sp = (const float4*)(states + (size_t)g * 128 + q4 * 32);
                float4 v[8];
#pragma unroll
                for (int i = 0; i < 8; ++i) v[i] = sp[i];
#pragma unroll
                for (int i = 0; i < 8; ++i) {
                    int col = (q4 * 32 + i * 4 + rot) & 127;
                    ushort4 o;
                    o.x = f2bf(v[i].x); o.y = f2bf(v[i].y);
                    o.z = f2bf(v[i].z); o.w = f2bf(v[i].w);
                    *(ushort4*)(dstRow + col) = o;
                }
            } else {
#pragma unroll
                for (int i = 0; i < 8; ++i) {
                    int col = (q4 * 32 + i * 4 + rot) & 127;
                    *(ushort4*)(dstRow + col) = ushort4{0, 0, 0, 0};
                }
            }
        }
        __syncthreads();

        loadW(2, wfY);                       // C1, issued early; latency hidden under gemm1

        // ---- phase 1: h = relu(A@W1 + b1) -> Hbuf (swizzled) ----
        gemm(Abuf, wfX, acc);
#pragma unroll
        for (int mg = 0; mg < 4; ++mg)
#pragma unroll
            for (int nn = 0; nn < 2; ++nn) {
                int col = (wv * 2 + nn) * 16 + l15;
#pragma unroll
                for (int r = 0; r < 4; ++r) {
                    int row = mg * 16 + quad * 4 + r;
                    float v = fmaxf(acc[mg][nn][r] + b1v[nn], 0.f);
                    Hbuf[row * 128 + ((col + ((row & 15) << 3)) & 127)] = f2bf(v);
                }
            }

        loadW(1, wfX);                       // W2 (wfX free after gemm1); hidden under gemm3

        // ---- phase 3: classifier partials (this wave's 32 cols), reads Abuf ----
        gemm(Abuf, wfY, acc);
        {
            float part[4][4];
#pragma unroll
            for (int mg = 0; mg < 4; ++mg)
#pragma unroll
                for (int r = 0; r < 4; ++r) part[mg][r] = 0.f;
#pragma unroll
            for (int nn = 0; nn < 2; ++nn) {
                int col = (wv * 2 + nn) * 16 + l15;
                float cw = C2s[col];
#pragma unroll
                for (int mg = 0; mg < 4; ++mg)
#pragma unroll
                    for (int r = 0; r < 4; ++r)
                        part[mg][r] += fmaxf(acc[mg][nn][r] + c1v[nn], 0.f) * cw;
            }
#pragma unroll
            for (int off = 1; off < 16; off <<= 1)
#pragma unroll
                for (int mg = 0; mg < 4; ++mg)
#pragma unroll
                    for (int r = 0; r < 4; ++r)
                        part[mg][r] += __shfl_xor(part[mg][r], off, 64);
            if (l15 == 0) {
#pragma unroll
                for (int mg = 0; mg < 4; ++mg)
#pragma unroll
                    for (int r = 0; r < 4; ++r)
                        pLds[wv][mg * 16 + quad * 4 + r] = part[mg][r];
            }
        }
        __syncthreads();

        // ---- phase 2: y = h@W2 + b2 -> scatter out_state ----
        gemm(Hbuf, wfX, acc);
#pragma unroll
        for (int mg = 0; mg < 4; ++mg) {
            int gr4[4];
#pragma unroll
            for (int r = 0; r < 4; ++r) gr4[r] = gIdxLds[mg * 16 + quad * 4 + r];
#pragma unroll
            for (int nn = 0; nn < 2; ++nn) {
                int col = (wv * 2 + nn) * 16 + l15;
                float bias = b2v[nn];
#pragma unroll
                for (int r = 0; r < 4; ++r)
                    if (gr4[r] >= 0) out_state[(size_t)gr4[r] * 128 + col] = acc[mg][nn][r] + bias;
            }
        }

        // ---- epilogue: cross-wave sum, sigmoid, min, store (wave 0 only) ----
        if (t < 64) {
            int eg = gIdxLds[t];
            if (eg >= 0) {
                float tot = pLds[0][t] + pLds[1][t] + pLds[2][t] + pLds[3][t] + c2s;
                float cls = 1.f / (1.f + expf(-tot));
                out_score[eg] = fminf(scoreLds[t], cls);
            }
        }

        // only needed when this block has another tile (pathological imbalance):
        // protects Abuf/gIdxLds/scoreLds from next stage while gemm2/epilogue read them
        if (tile + (int)gridDim.x < ntiles) __syncthreads();
    }
}

extern "C" void kernel_launch(void* const* d_in, const int* in_sizes, int n_in,
                              void* d_out, int out_size, void* d_ws, size_t ws_size,
                              hipStream_t stream) {
    const float* states = (const float*)d_in[0];
    const float* scores = (const float*)d_in[1];
    const int*   type_ids = (const int*)d_in[2];
    const float* tm = (const float*)d_in[3];
    const float* W1 = (const float*)d_in[4];
    const float* b1 = (const float*)d_in[5];
    const float* W2 = (const float*)d_in[6];
    const float* b2 = (const float*)d_in[7];
    const float* C1 = (const float*)d_in[8];
    const float* c1 = (const float*)d_in[9];
    const float* C2 = (const float*)d_in[10];
    const float* c2 = (const float*)d_in[11];

    char* ws = (char*)d_ws;
    int*   counts  = (int*)(ws + 0);                        // 4 ints (poison-initialized 0xAA)
    int*   buckets = (int*)(ws + 4096);                     // 4 * 65536 ints = 1 MB
    unsigned short* wbf = (unsigned short*)(ws + 1052672);  // 12 * 16384 bf16, frag-linear

    float* out_state = (float*)d_out;                       // N*128
    float* out_score = out_state + (size_t)Nn * 128;        // N
    float* out_prob  = out_score + Nn;                      // N

    k_prep<<<448, 256, 0, stream>>>(type_ids, tm, W1, W2, C1, counts, buckets, wbf, out_prob);
    k_main<<<dim3(288, 4), 256, 0, stream>>>(states, scores, b1, b2, c1,
        tm, C2, c2, counts, buckets, wbf, out_state, out_score);
}

// Round 2
// 163.842 us; speedup vs baseline: 1.0496x; 1.0496x over previous
//
#include <hip/hip_runtime.h>
#include <math.h>

#define Nn 65536

typedef short s16x8 __attribute__((ext_vector_type(8)));
typedef float f32x4 __attribute__((ext_vector_type(4)));
typedef unsigned int u32;

__device__ __forceinline__ unsigned short f2bf(float x) {
    u32 u = __float_as_uint(x);
    u += 0x7FFFu + ((u >> 16) & 1u);
    return (unsigned short)(u >> 16);
}

// argmax over row s of the 4x4 type_matching (first max wins, matches jnp.argmax)
__device__ __forceinline__ int best_t_for(const float* __restrict__ tm, int s, float* mOut) {
    float m = tm[s * 4];
    int am = 0;
#pragma unroll
    for (int j = 1; j < 4; ++j) {
        float v = tm[s * 4 + j];
        if (v > m) { m = v; am = j; }
    }
    if (mOut) *mOut = m;
    return am;
}

// ============ k_prep: blocks 0-63 partition (ballot-prefix, poison-CAS), 64-159 weight convert ============
__global__ void k_prep(const int* __restrict__ type_ids, const float* __restrict__ tm,
                       const float* __restrict__ W1, const float* __restrict__ W2,
                       const float* __restrict__ C1,
                       int* __restrict__ counts, int* __restrict__ buckets,
                       unsigned short* __restrict__ wbf, float* __restrict__ out_prob) {
    const int tid = threadIdx.x;
    if (blockIdx.x < 64) {
        __shared__ float prob[4];
        __shared__ int cntL[4][4][4];   // [wave][j][type]
        __shared__ int baseL[4][4];     // [wave][type]
        if (tid < 4) {
            float m;
            best_t_for(tm, tid, &m);
            prob[tid] = 1.f / (1.f + expf(-m));
        }
        const int gid = blockIdx.x * 256 + tid;    // int4 index
        int4 ids = ((const int4*)type_ids)[gid];
        int idarr[4] = {ids.x, ids.y, ids.z, ids.w};
        const int lane = tid & 63;
        const int wv = tid >> 6;
        const unsigned long long lt = (1ull << lane) - 1ull;
        unsigned long long msk[4];
        // pass 1: per-wave per-j per-type counts via ballot (no atomics)
#pragma unroll
        for (int j = 0; j < 4; ++j) {
            int idj = idarr[j];
#pragma unroll
            for (int sv = 0; sv < 4; ++sv) {
                unsigned long long m = __ballot(idj == sv);
                if (idj == sv) msk[j] = m;
                if (lane == 0) cntL[wv][j][sv] = (int)__popcll(m);
            }
        }
        __syncthreads();
        float4 p;
        p.x = prob[idarr[0]]; p.y = prob[idarr[1]];
        p.z = prob[idarr[2]]; p.w = prob[idarr[3]];
        ((float4*)out_prob)[gid] = p;
        if (tid < 4) {
            const int sv = tid;
            int wsum[4];
#pragma unroll
            for (int w = 0; w < 4; ++w) {
                wsum[w] = cntL[w][0][sv] + cntL[w][1][sv] + cntL[w][2][sv] + cntL[w][3][sv];
            }
            int tot = wsum[0] + wsum[1] + wsum[2] + wsum[3];
            // poison-CAS reservation: no memset node needed (counts harness-poisoned 0xAAAAAAAA)
            u32 old = atomicCAS((u32*)&counts[sv], 0xAAAAAAAAu, (u32)tot);
            int b = (old == 0xAAAAAAAAu) ? 0 : atomicAdd(&counts[sv], tot);
#pragma unroll
            for (int w = 0; w < 4; ++w) { baseL[w][sv] = b; b += wsum[w]; }
        }
        __syncthreads();
        // pass 2: unique position = wave base + j-prefix + lane-prefix
        const int gbase = gid * 4;
#pragma unroll
        for (int j = 0; j < 4; ++j) {
            int sv = idarr[j];
            int off = baseL[wv][sv];
#pragma unroll
            for (int jp = 0; jp < 4; ++jp)
                if (jp < j) off += cntL[wv][jp][sv];
            off += (int)__popcll(msk[j] & lt);
            buckets[sv * Nn + off] = gbase + j;
        }
    } else {
        // weight convert: fp32 [D][H] -> bf16 fragment-linear for 12 live matrices
        int u = (blockIdx.x - 64) * 256 + tid;      // 0..24575
        int mat = u >> 11;
        int rr = u & 2047;
        int f = rr >> 6, lane = rr & 63;
        int kk = f >> 3, n8 = f & 7;
        int q = lane >> 4, l15 = lane & 15;
        int sm = mat / 3, w = mat - sm * 3;
        int t = best_t_for(tm, sm, nullptr);
        const float* src = (w == 0) ? W1 : (w == 1) ? W2 : C1;
        const float* sp = src + (((sm * 4 + t) << 14) + n8 * 16 + l15);
        int k0 = kk * 32 + q * 8;
        s16x8 o;
#pragma unroll
        for (int j = 0; j < 8; ++j) o[j] = (short)f2bf(sp[(k0 + j) * 128]);
        *(s16x8*)(wbf + (size_t)u * 8) = o;
    }
}

// ================= k_main: Round-0 structure + single weight set reloaded per phase =================
// Grid (128,4), 2 balanced tiles/block, double-buffered A, prefetch distance 128.
// ONE 32-reg wf set (vs 96-reg wf[3]): each phase's weights reloaded from L2-resident wbf,
// issued immediately after the previous gemm frees the registers, so the ~300cyc L2 latency
// hides under the epilogue/barrier. This fits __launch_bounds__(256,3) (170-reg budget)
// without spill -> 12 waves/CU instead of 8.
// A/H layout: row*128 + ((col + (row&15)*8) & 127)  -- pad-free, conflict-free b128 frags
__global__ __launch_bounds__(256, 3) void k_main(
    const float* __restrict__ states, const float* __restrict__ scores,
    const float* __restrict__ b1g, const float* __restrict__ b2g, const float* __restrict__ c1g,
    const float* __restrict__ tm, const float* __restrict__ C2, const float* __restrict__ c2,
    const int* __restrict__ counts, const int* __restrict__ buckets,
    const unsigned short* __restrict__ wbf,
    float* __restrict__ out_state, float* __restrict__ out_score)
{
    __shared__ __align__(16) unsigned short Abuf[2][64 * 128];  // 2 x 16 KB
    __shared__ __align__(16) unsigned short Hbuf[64 * 128];     // 16 KB
    __shared__ int gIdxLds[2][64];
    __shared__ float scoreLds[2][64];
    __shared__ float pLds[4][64];
    __shared__ float C2s[128];

    const int s = blockIdx.y;
    const int cnt = counts[s];
    const int ntiles = (cnt + 63) >> 6;
    const int bx = blockIdx.x;
    if (bx >= ntiles) return;
    const int t = threadIdx.x;
    const int tt = best_t_for(tm, s, nullptr);
    const int stIdx = s * 4 + tt;

    const int lane = t & 63;
    const int wv = t >> 6;           // wave -> 32-col slice (n-groups 2wv, 2wv+1)
    const int l15 = lane & 15;
    const int quad = lane >> 4;
    const int myRow = t >> 2;        // A staging: 4 threads per row
    const int q4 = t & 3;

    if (t >= 128) C2s[t - 128] = C2[stIdx * 128 + (t - 128)];

    // hoisted per-lane bias/weight constants
    float b1v[2], b2v[2], c1v[2];
#pragma unroll
    for (int nn = 0; nn < 2; ++nn) {
        int col = (wv * 2 + nn) * 16 + l15;
        b1v[nn] = b1g[stIdx * 128 + col];
        b2v[nn] = b2g[stIdx * 128 + col];
        c1v[nn] = c1g[stIdx * 128 + col];
    }
    const float c2s = c2[stIdx];
    const int* bkt = buckets + s * Nn;
    const unsigned short* wb = wbf + (size_t)s * 3 * 16384;

    // single weight fragment set, reloaded per phase from L2-resident wbf
    s16x8 wf[4][2];
    auto loadW = [&](int m) {
#pragma unroll
        for (int kk = 0; kk < 4; ++kk)
#pragma unroll
            for (int nn = 0; nn < 2; ++nn)
                wf[kk][nn] = *(const s16x8*)(wb + m * 16384 +
                    (size_t)((kk * 8 + (wv * 2 + nn)) * 64 + lane) * 8);
    };

    // gemm: A-frags from swizzled LDS, B-frags from wf registers
    auto gemm = [&](const unsigned short* Ab, f32x4 acc[4][2]) {
#pragma unroll
        for (int mg = 0; mg < 4; ++mg)
#pragma unroll
            for (int nn = 0; nn < 2; ++nn) acc[mg][nn] = f32x4{0.f, 0.f, 0.f, 0.f};
#pragma unroll
        for (int kk = 0; kk < 4; ++kk) {
            const int colsw = (kk * 32 + quad * 8 + l15 * 8) & 127;  // row&15 == l15
            s16x8 af[4];
#pragma unroll
            for (int mg = 0; mg < 4; ++mg)
                af[mg] = *(const s16x8*)(Ab + (mg * 16 + l15) * 128 + colsw);
#pragma unroll
            for (int mg = 0; mg < 4; ++mg)
#pragma unroll
                for (int nn = 0; nn < 2; ++nn)
                    acc[mg][nn] = __builtin_amdgcn_mfma_f32_16x16x32_bf16(
                        af[mg], wf[kk][nn], acc[mg][nn], 0, 0, 0);
        }
    };

    // ---- prologue: stage tile0 (W1 fragments load in parallel with HBM stage) ----
    loadW(0);
    {
        int gr = bx * 64 + myRow;
        int g = (gr < cnt) ? bkt[gr] : -1;
        if (q4 == 0) {
            gIdxLds[0][myRow] = g;
            scoreLds[0][myRow] = (g >= 0) ? scores[g] : 0.f;
        }
        unsigned short* dstRow = &Abuf[0][myRow * 128];
        const int rot = (myRow & 15) << 3;
        if (g >= 0) {
            const float4* sp = (const float4*)(states + (size_t)g * 128 + q4 * 32);
            float4 v[8];
#pragma unroll
            for (int i = 0; i < 8; ++i) v[i] = sp[i];
#pragma unroll
            for (int i = 0; i < 8; ++i) {
                int col = (q4 * 32 + i * 4 + rot) & 127;
                ushort4 o;
                o.x = f2bf(v[i].x); o.y = f2bf(v[i].y);
                o.z = f2bf(v[i].z); o.w = f2bf(v[i].w);
                *(ushort4*)(dstRow + col) = o;
            }
        } else {
#pragma unroll
            for (int i = 0; i < 8; ++i) {
                int col = (q4 * 32 + i * 4 + rot) & 127;
                *(ushort4*)(dstRow + col) = ushort4{0, 0, 0, 0};
            }
        }
    }
    int rIdxN = -1;
    if (bx + 128 < ntiles) {
        int gr = (bx + 128) * 64 + myRow;
        rIdxN = (gr < cnt) ? bkt[gr] : -1;
    }
    __syncthreads();

    f32x4 acc[4][2];
    int cur = 0;
    for (int tile = bx; tile < ntiles; tile += 128, cur ^= 1) {
        const int nxt = cur ^ 1;
        const bool hasNext = (tile + 128) < ntiles;

        // ---- phase 1: h = relu(A@W1 + b1) -> Hbuf (swizzled); wf holds W1 ----
        gemm(Abuf[cur], acc);
        loadW(1);   // W2: regs free after gemm1's last MFMA; latency hides under epilogue+barrier
#pragma unroll
        for (int mg = 0; mg < 4; ++mg)
#pragma unroll
            for (int nn = 0; nn < 2; ++nn) {
                int col = (wv * 2 + nn) * 16 + l15;
#pragma unroll
                for (int r = 0; r < 4; ++r) {
                    int row = mg * 16 + quad * 4 + r;
                    float v = fmaxf(acc[mg][nn][r] + b1v[nn], 0.f);
                    Hbuf[row * 128 + ((col + ((row & 15) << 3)) & 127)] = f2bf(v);
                }
            }
        if (q4 == 0) gIdxLds[nxt][myRow] = rIdxN;
        __syncthreads();

        // ---- prefetch next tile's A + score (overlaps gemm2/3) ----
        float4 pf[8];
        float scN = 0.f;
        if (hasNext && rIdxN >= 0) {
            const float4* sp = (const float4*)(states + (size_t)rIdxN * 128 + q4 * 32);
#pragma unroll
            for (int i = 0; i < 8; ++i) pf[i] = sp[i];
            scN = scores[rIdxN];
        }
        int rIdxN2 = -1;
        if (tile + 256 < ntiles) {
            int gr = (tile + 256) * 64 + myRow;
            rIdxN2 = (gr < cnt) ? bkt[gr] : -1;
        }

        // ---- phase 2: y = h@W2 + b2 -> scatter out_state; wf holds W2 ----
        gemm(Hbuf, acc);
        loadW(2);   // C1: latency hides under the scatter stores
#pragma unroll
        for (int mg = 0; mg < 4; ++mg) {
            int gr4[4];
#pragma unroll
            for (int r = 0; r < 4; ++r) gr4[r] = gIdxLds[cur][mg * 16 + quad * 4 + r];
#pragma unroll
            for (int nn = 0; nn < 2; ++nn) {
                int col = (wv * 2 + nn) * 16 + l15;
                float bias = b2v[nn];
#pragma unroll
                for (int r = 0; r < 4; ++r)
                    if (gr4[r] >= 0) out_state[(size_t)gr4[r] * 128 + col] = acc[mg][nn][r] + bias;
            }
        }

        // ---- phase 3: classifier partials (this wave's 32 cols); wf holds C1 ----
        gemm(Abuf[cur], acc);
        loadW(0);   // W1 for next tile: latency hides under reduce+commit+barrier
        {
            float part[4][4];
#pragma unroll
            for (int mg = 0; mg < 4; ++mg)
#pragma unroll
                for (int r = 0; r < 4; ++r) part[mg][r] = 0.f;
#pragma unroll
            for (int nn = 0; nn < 2; ++nn) {
                int col = (wv * 2 + nn) * 16 + l15;
                float cw = C2s[col];
#pragma unroll
                for (int mg = 0; mg < 4; ++mg)
#pragma unroll
                    for (int r = 0; r < 4; ++r)
                        part[mg][r] += fmaxf(acc[mg][nn][r] + c1v[nn], 0.f) * cw;
            }
#pragma unroll
            for (int off = 1; off < 16; off <<= 1)
#pragma unroll
                for (int mg = 0; mg < 4; ++mg)
#pragma unroll
                    for (int r = 0; r < 4; ++r)
                        part[mg][r] += __shfl_xor(part[mg][r], off, 64);
            if (l15 == 0) {
#pragma unroll
                for (int mg = 0; mg < 4; ++mg)
#pragma unroll
                    for (int r = 0; r < 4; ++r)
                        pLds[wv][mg * 16 + quad * 4 + r] = part[mg][r];
            }
        }

        // ---- commit prefetched A into Abuf[nxt] ----
        if (hasNext) {
            unsigned short* dstRow = &Abuf[nxt][myRow * 128];
            const int rot = (myRow & 15) << 3;
            if (rIdxN >= 0) {
#pragma unroll
                for (int i = 0; i < 8; ++i) {
                    int col = (q4 * 32 + i * 4 + rot) & 127;
                    ushort4 o;
                    o.x = f2bf(pf[i].x); o.y = f2bf(pf[i].y);
                    o.z = f2bf(pf[i].z); o.w = f2bf(pf[i].w);
                    *(ushort4*)(dstRow + col) = o;
                }
            } else {
#pragma unroll
                for (int i = 0; i < 8; ++i) {
                    int col = (q4 * 32 + i * 4 + rot) & 127;
                    *(ushort4*)(dstRow + col) = ushort4{0, 0, 0, 0};
                }
            }
            if (q4 == 0) scoreLds[nxt][myRow] = (rIdxN >= 0) ? scN : 0.f;
        }

        // stash epilogue-3 inputs in regs BEFORE the barrier (avoids race with next
        // iteration's gIdxLds[nxt] write, which targets this slot)
        int eg = -1;
        float esc = 0.f;
        if (t < 64) { eg = gIdxLds[cur][t]; esc = scoreLds[cur][t]; }
        rIdxN = rIdxN2;
        __syncthreads();

        // ---- epilogue 3: cross-wave sum, sigmoid, min, store (wave 0 only) ----
        if (t < 64 && eg >= 0) {
            float tot = pLds[0][t] + pLds[1][t] + pLds[2][t] + pLds[3][t] + c2s;
            float cls = 1.f / (1.f + expf(-tot));
            out_score[eg] = fminf(esc, cls);
        }
    }
}

extern "C" void kernel_launch(void* const* d_in, const int* in_sizes, int n_in,
                              void* d_out, int out_size, void* d_ws, size_t ws_size,
                              hipStream_t stream) {
    const float* states = (const float*)d_in[0];
    const float* scores = (const float*)d_in[1];
    const int*   type_ids = (const int*)d_in[2];
    const float* tm = (const float*)d_in[3];
    const float* W1 = (const float*)d_in[4];
    const float* b1 = (const float*)d_in[5];
    const float* W2 = (const float*)d_in[6];
    const float* b2 = (const float*)d_in[7];
    const float* C1 = (const float*)d_in[8];
    const float* c1 = (const float*)d_in[9];
    const float* C2 = (const float*)d_in[10];
    const float* c2 = (const float*)d_in[11];

    char* ws = (char*)d_ws;
    int*   counts  = (int*)(ws + 0);                        // 4 ints (poison-initialized 0xAA)
    int*   buckets = (int*)(ws + 4096);                     // 4 * 65536 ints = 1 MB
    unsigned short* wbf = (unsigned short*)(ws + 1052672);  // 12 * 16384 bf16, frag-linear

    float* out_state = (float*)d_out;                       // N*128
    float* out_score = out_state + (size_t)Nn * 128;        // N
    float* out_prob  = out_score + Nn;                      // N

    k_prep<<<160, 256, 0, stream>>>(type_ids, tm, W1, W2, C1, counts, buckets, wbf, out_prob);
    k_main<<<dim3(128, 4), 256, 0, stream>>>(states, scores, b1, b2, c1,
        tm, C2, c2, counts, buckets, wbf, out_state, out_score);
}

// Round 3
// 133.437 us; speedup vs baseline: 1.2887x; 1.2279x over previous
//
#include <hip/hip_runtime.h>
#include <math.h>

#define Nn 65536

typedef short s16x8 __attribute__((ext_vector_type(8)));
typedef float f32x4 __attribute__((ext_vector_type(4)));
typedef unsigned int u32;

__device__ __forceinline__ unsigned short f2bf(float x) {
    u32 u = __float_as_uint(x);
    u += 0x7FFFu + ((u >> 16) & 1u);
    return (unsigned short)(u >> 16);
}

// argmax over row s of the 4x4 type_matching (first max wins, matches jnp.argmax)
__device__ __forceinline__ int best_t_for(const float* __restrict__ tm, int s, float* mOut) {
    float m = tm[s * 4];
    int am = 0;
#pragma unroll
    for (int j = 1; j < 4; ++j) {
        float v = tm[s * 4 + j];
        if (v > m) { m = v; am = j; }
    }
    if (mOut) *mOut = m;
    return am;
}

// ============ k_prep ============
// blocks 0..255   : partition, 1 item/thread, ballot-prefix positions (no per-item atomics),
//                   poison-CAS global reservation on counts[]
// blocks 256..351 : weight convert fp32 [D][H] -> bf16 fragment-linear for 12 live matrices
__global__ void k_prep(const int* __restrict__ type_ids, const float* __restrict__ tm,
                       const float* __restrict__ W1, const float* __restrict__ W2,
                       const float* __restrict__ C1,
                       int* __restrict__ counts, int* __restrict__ buckets,
                       unsigned short* __restrict__ wbf, float* __restrict__ out_prob) {
    const int tid = threadIdx.x;
    if (blockIdx.x < 256) {
        __shared__ float prob[4];
        __shared__ int waveCnt[4][4];   // [wave][type]
        __shared__ int waveBase[4][4];
        if (tid < 4) {
            float m;
            best_t_for(tm, tid, &m);
            prob[tid] = 1.f / (1.f + expf(-m));
        }
        __syncthreads();
        const int gid = blockIdx.x * 256 + tid;
        const int id = type_ids[gid];
        out_prob[gid] = prob[id];
        const int lane = tid & 63;
        const int wvv = tid >> 6;
        const unsigned long long lt = (1ull << lane) - 1ull;
        int myPrefix = 0;
#pragma unroll
        for (int sv = 0; sv < 4; ++sv) {
            unsigned long long m = __ballot(id == sv);
            if (id == sv) myPrefix = (int)__popcll(m & lt);
            if (lane == 0) waveCnt[wvv][sv] = (int)__popcll(m);
        }
        __syncthreads();
        if (tid < 4) {
            const int sv = tid;
            int c0 = waveCnt[0][sv], c1 = waveCnt[1][sv];
            int c2_ = waveCnt[2][sv], c3 = waveCnt[3][sv];
            int tot = c0 + c1 + c2_ + c3;
            // poison-CAS reservation: no memset node needed (counts harness-poisoned 0xAAAAAAAA)
            u32 old = atomicCAS((u32*)&counts[sv], 0xAAAAAAAAu, (u32)tot);
            int b = (old == 0xAAAAAAAAu) ? 0 : atomicAdd(&counts[sv], tot);
            waveBase[0][sv] = b;
            waveBase[1][sv] = b + c0;
            waveBase[2][sv] = b + c0 + c1;
            waveBase[3][sv] = b + c0 + c1 + c2_;
        }
        __syncthreads();
        buckets[id * Nn + waveBase[wvv][id] + myPrefix] = gid;
    } else {
        // weight convert: fp32 [D][H] -> bf16 fragment-linear for 12 live matrices
        int u = (blockIdx.x - 256) * 256 + tid;     // 0..24575
        int mat = u >> 11;
        int rr = u & 2047;
        int f = rr >> 6, lane = rr & 63;
        int kk = f >> 3, n8 = f & 7;
        int q = lane >> 4, l15 = lane & 15;
        int sm = mat / 3, w = mat - sm * 3;
        int t = best_t_for(tm, sm, nullptr);
        const float* src = (w == 0) ? W1 : (w == 1) ? W2 : C1;
        const float* sp = src + (((sm * 4 + t) << 14) + n8 * 16 + l15);
        int k0 = kk * 32 + q * 8;
        s16x8 o;
#pragma unroll
        for (int j = 0; j < 8; ++j) o[j] = (short)f2bf(sp[(k0 + j) * 128]);
        *(s16x8*)(wbf + (size_t)u * 8) = o;
    }
}

// ================= k_main: 8-wave blocks, 16 cols/wave, low register demand =================
// The round-0 structure was latency-bound at 2 blocks/CU (grid-limited; MFMA 5%, VALU 10%,
// HBM 16%). Rounds 1-2 proved cutting the register CAP below demand (~170) spills (+90 MB
// scratch HBM traffic). This version cuts DEMAND instead: 8 waves x 16-col slices ->
// wf[3][4]=48 regs (vs 96), acc[4]=16 (vs 32), staging v[4]=16. Peak ~110 unified regs
// fits __launch_bounds__(512,4)'s 128-reg cap -> 16 waves/CU, 2 blocks/CU, and
// grid (128,4) = 4096 waves = exactly full single-generation residency.
// A/H layout: row*128 + ((col + (row&15)*8) & 127)  -- pad-free, conflict-free b128 frags
__global__ __launch_bounds__(512, 4) void k_main(
    const float* __restrict__ states, const float* __restrict__ scores,
    const float* __restrict__ b1g, const float* __restrict__ b2g, const float* __restrict__ c1g,
    const float* __restrict__ tm, const float* __restrict__ C2, const float* __restrict__ c2,
    const int* __restrict__ counts, const int* __restrict__ buckets,
    const unsigned short* __restrict__ wbf,
    float* __restrict__ out_state, float* __restrict__ out_score)
{
    __shared__ __align__(16) unsigned short Abuf[64 * 128];   // 16 KB
    __shared__ __align__(16) unsigned short Hbuf[64 * 128];   // 16 KB
    __shared__ int gIdxLds[64];
    __shared__ float scoreLds[64];
    __shared__ float pLds[8][64];                             // 2 KB

    const int s = blockIdx.y;
    const int cnt = counts[s];
    const int ntiles = (cnt + 63) >> 6;
    const int bx = blockIdx.x;
    if (bx >= ntiles) return;
    const int t = threadIdx.x;
    const int tt = best_t_for(tm, s, nullptr);
    const int stIdx = s * 4 + tt;

    const int lane = t & 63;
    const int wv = t >> 6;           // wave 0..7 -> 16-col slice
    const int l15 = lane & 15;
    const int quad = lane >> 4;
    const int myRow = t >> 3;        // A staging: 8 threads per row
    const int q8 = t & 7;
    const int col = wv * 16 + l15;   // this lane's output column

    // per-lane bias/weight constants (single column per lane now)
    const float b1v = b1g[stIdx * 128 + col];
    const float b2v = b2g[stIdx * 128 + col];
    const float c1v = c1g[stIdx * 128 + col];
    const float c2w = C2[stIdx * 128 + col];
    const float c2s = c2[stIdx];
    const int* bkt = buckets + s * Nn;
    const unsigned short* wb = wbf + (size_t)s * 3 * 16384;

    // all 3 matrices' fragments for this wave's 16-col slice: 3*4*4 = 48 VGPRs, loaded once
    s16x8 wf[3][4];
#pragma unroll
    for (int m = 0; m < 3; ++m)
#pragma unroll
        for (int kk = 0; kk < 4; ++kk)
            wf[m][kk] = *(const s16x8*)(wb + m * 16384 +
                (size_t)((kk * 8 + wv) * 64 + lane) * 8);

    // gemm: A-frags from swizzled LDS, B-frags from registers (one 16-col slice)
    auto gemm = [&](const unsigned short* Ab, const s16x8 (&wfm)[4], f32x4 acc[4]) {
#pragma unroll
        for (int mg = 0; mg < 4; ++mg) acc[mg] = f32x4{0.f, 0.f, 0.f, 0.f};
#pragma unroll
        for (int kk = 0; kk < 4; ++kk) {
            const int colsw = (kk * 32 + quad * 8 + l15 * 8) & 127;  // row&15 == l15
            s16x8 af[4];
#pragma unroll
            for (int mg = 0; mg < 4; ++mg)
                af[mg] = *(const s16x8*)(Ab + (mg * 16 + l15) * 128 + colsw);
#pragma unroll
            for (int mg = 0; mg < 4; ++mg)
                acc[mg] = __builtin_amdgcn_mfma_f32_16x16x32_bf16(
                    af[mg], wfm[kk], acc[mg], 0, 0, 0);
        }
    };

    f32x4 acc[4];
    for (int tile = bx; tile < ntiles; tile += gridDim.x) {
        if (tile != bx) __syncthreads();   // protect LDS from previous iteration's readers

        // ---- stage tile's A rows -> swizzled bf16 LDS (8 threads/row, 16 elems each) ----
        {
            int gr = tile * 64 + myRow;
            int g = (gr < cnt) ? bkt[gr] : -1;
            if (q8 == 0) {
                gIdxLds[myRow] = g;
                scoreLds[myRow] = (g >= 0) ? scores[g] : 0.f;
            }
            unsigned short* dstRow = &Abuf[myRow * 128];
            const int rot = (myRow & 15) << 3;
            if (g >= 0) {
                const float4* sp = (const float4*)(states + (size_t)g * 128 + q8 * 16);
                float4 v[4];
#pragma unroll
                for (int i = 0; i < 4; ++i) v[i] = sp[i];
#pragma unroll
                for (int i = 0; i < 4; ++i) {
                    int c = (q8 * 16 + i * 4 + rot) & 127;
                    ushort4 o;
                    o.x = f2bf(v[i].x); o.y = f2bf(v[i].y);
                    o.z = f2bf(v[i].z); o.w = f2bf(v[i].w);
                    *(ushort4*)(dstRow + c) = o;
                }
            } else {
#pragma unroll
                for (int i = 0; i < 4; ++i) {
                    int c = (q8 * 16 + i * 4 + rot) & 127;
                    *(ushort4*)(dstRow + c) = ushort4{0, 0, 0, 0};
                }
            }
        }
        __syncthreads();

        // ---- phase 1: h = relu(A@W1 + b1) -> Hbuf (swizzled) ----
        gemm(Abuf, wf[0], acc);
#pragma unroll
        for (int mg = 0; mg < 4; ++mg)
#pragma unroll
            for (int r = 0; r < 4; ++r) {
                int row = mg * 16 + quad * 4 + r;
                float v = fmaxf(acc[mg][r] + b1v, 0.f);
                Hbuf[row * 128 + ((col + ((row & 15) << 3)) & 127)] = f2bf(v);
            }
        __syncthreads();

        // ---- phase 2: y = h@W2 + b2 -> scatter out_state ----
        gemm(Hbuf, wf[1], acc);
#pragma unroll
        for (int mg = 0; mg < 4; ++mg) {
            int gr4[4];
#pragma unroll
            for (int r = 0; r < 4; ++r) gr4[r] = gIdxLds[mg * 16 + quad * 4 + r];
#pragma unroll
            for (int r = 0; r < 4; ++r)
                if (gr4[r] >= 0) out_state[(size_t)gr4[r] * 128 + col] = acc[mg][r] + b2v;
        }

        // ---- phase 3: classifier partials (this wave's 16 cols) ----
        gemm(Abuf, wf[2], acc);
        {
            float part[4][4];
#pragma unroll
            for (int mg = 0; mg < 4; ++mg)
#pragma unroll
                for (int r = 0; r < 4; ++r)
                    part[mg][r] = fmaxf(acc[mg][r] + c1v, 0.f) * c2w;
#pragma unroll
            for (int off = 1; off < 16; off <<= 1)
#pragma unroll
                for (int mg = 0; mg < 4; ++mg)
#pragma unroll
                    for (int r = 0; r < 4; ++r)
                        part[mg][r] += __shfl_xor(part[mg][r], off, 64);
            if (l15 == 0) {
#pragma unroll
                for (int mg = 0; mg < 4; ++mg)
#pragma unroll
                    for (int r = 0; r < 4; ++r)
                        pLds[wv][mg * 16 + quad * 4 + r] = part[mg][r];
            }
        }
        __syncthreads();

        // ---- epilogue: cross-wave sum, sigmoid, min, store (first 64 lanes) ----
        if (t < 64) {
            int eg = gIdxLds[t];
            if (eg >= 0) {
                float tot = pLds[0][t] + pLds[1][t] + pLds[2][t] + pLds[3][t]
                          + pLds[4][t] + pLds[5][t] + pLds[6][t] + pLds[7][t] + c2s;
                float cls = 1.f / (1.f + expf(-tot));
                out_score[eg] = fminf(scoreLds[t], cls);
            }
        }
    }
}

extern "C" void kernel_launch(void* const* d_in, const int* in_sizes, int n_in,
                              void* d_out, int out_size, void* d_ws, size_t ws_size,
                              hipStream_t stream) {
    const float* states = (const float*)d_in[0];
    const float* scores = (const float*)d_in[1];
    const int*   type_ids = (const int*)d_in[2];
    const float* tm = (const float*)d_in[3];
    const float* W1 = (const float*)d_in[4];
    const float* b1 = (const float*)d_in[5];
    const float* W2 = (const float*)d_in[6];
    const float* b2 = (const float*)d_in[7];
    const float* C1 = (const float*)d_in[8];
    const float* c1 = (const float*)d_in[9];
    const float* C2 = (const float*)d_in[10];
    const float* c2 = (const float*)d_in[11];

    char* ws = (char*)d_ws;
    int*   counts  = (int*)(ws + 0);                        // 4 ints (poison-initialized 0xAA)
    int*   buckets = (int*)(ws + 4096);                     // 4 * 65536 ints = 1 MB
    unsigned short* wbf = (unsigned short*)(ws + 1052672);  // 12 * 16384 bf16, frag-linear

    float* out_state = (float*)d_out;                       // N*128
    float* out_score = out_state + (size_t)Nn * 128;        // N
    float* out_prob  = out_score + Nn;                      // N

    k_prep<<<352, 256, 0, stream>>>(type_ids, tm, W1, W2, C1, counts, buckets, wbf, out_prob);
    k_main<<<dim3(128, 4), 512, 0, stream>>>(states, scores, b1, b2, c1,
        tm, C2, c2, counts, buckets, wbf, out_state, out_score);
}

// Round 4
// 129.739 us; speedup vs baseline: 1.3255x; 1.0285x over previous
//
#include <hip/hip_runtime.h>
#include <math.h>

#define Nn 65536

typedef short s16x8 __attribute__((ext_vector_type(8)));
typedef float f32x4 __attribute__((ext_vector_type(4)));
typedef unsigned int u32;

__device__ __forceinline__ unsigned short f2bf(float x) {
    u32 u = __float_as_uint(x);
    u += 0x7FFFu + ((u >> 16) & 1u);
    return (unsigned short)(u >> 16);
}

// argmax over row s of the 4x4 type_matching (first max wins, matches jnp.argmax)
__device__ __forceinline__ int best_t_for(const float* __restrict__ tm, int s, float* mOut) {
    float m = tm[s * 4];
    int am = 0;
#pragma unroll
    for (int j = 1; j < 4; ++j) {
        float v = tm[s * 4 + j];
        if (v > m) { m = v; am = j; }
    }
    if (mOut) *mOut = m;
    return am;
}

// ============ k_prep ============
// blocks 0..63  : partition, int4/thread, ballot-prefix positions (NO per-item atomics),
//                 poison-CAS reservation on per-type LINE-PADDED counters (countsPad[sv*64])
//                 -> 4 independent atomic chains of ~128 ops instead of 2048 ops on one line
// blocks 64..159: weight convert fp32 [D][H] -> bf16 fragment-linear for 12 live matrices
__global__ void k_prep(const int* __restrict__ type_ids, const float* __restrict__ tm,
                       const float* __restrict__ W1, const float* __restrict__ W2,
                       const float* __restrict__ C1,
                       int* __restrict__ countsPad, int* __restrict__ buckets,
                       unsigned short* __restrict__ wbf, float* __restrict__ out_prob) {
    const int tid = threadIdx.x;
    if (blockIdx.x < 64) {
        __shared__ float prob[4];
        __shared__ int cntL[4][4][4];   // [wave][j][type]
        __shared__ int baseW[4][4];     // [wave][type]
        if (tid < 4) {
            float m;
            best_t_for(tm, tid, &m);
            prob[tid] = 1.f / (1.f + expf(-m));
        }
        const int gid = blockIdx.x * 256 + tid;    // int4 index
        int4 ids = ((const int4*)type_ids)[gid];
        int idarr[4] = {ids.x, ids.y, ids.z, ids.w};
        const int lane = tid & 63;
        const int wv = tid >> 6;
        const unsigned long long lt = (1ull << lane) - 1ull;
        unsigned long long msk[4];
        // pass 1: per-wave per-j per-type counts via ballot (no atomics)
#pragma unroll
        for (int j = 0; j < 4; ++j) {
            int idj = idarr[j];
#pragma unroll
            for (int sv = 0; sv < 4; ++sv) {
                unsigned long long m = __ballot(idj == sv);
                if (idj == sv) msk[j] = m;
                if (lane == 0) cntL[wv][j][sv] = (int)__popcll(m);
            }
        }
        __syncthreads();
        float4 p;
        p.x = prob[idarr[0]]; p.y = prob[idarr[1]];
        p.z = prob[idarr[2]]; p.w = prob[idarr[3]];
        ((float4*)out_prob)[gid] = p;
        if (tid < 4) {
            const int sv = tid;
            int wsum[4];
#pragma unroll
            for (int w = 0; w < 4; ++w)
                wsum[w] = cntL[w][0][sv] + cntL[w][1][sv] + cntL[w][2][sv] + cntL[w][3][sv];
            int tot = wsum[0] + wsum[1] + wsum[2] + wsum[3];
            // poison-CAS reservation on this type's OWN cache line (no cross-type ping-pong)
            u32 old = atomicCAS((u32*)&countsPad[sv * 64], 0xAAAAAAAAu, (u32)tot);
            int b = (old == 0xAAAAAAAAu) ? 0 : atomicAdd(&countsPad[sv * 64], tot);
#pragma unroll
            for (int w = 0; w < 4; ++w) { baseW[w][sv] = b; b += wsum[w]; }
        }
        __syncthreads();
        // pass 2: unique position = wave base + j-prefix + lane-prefix
        const int gbase = gid * 4;
#pragma unroll
        for (int j = 0; j < 4; ++j) {
            int sv = idarr[j];
            int off = baseW[wv][sv];
#pragma unroll
            for (int jp = 0; jp < 4; ++jp)
                if (jp < j) off += cntL[wv][jp][sv];
            off += (int)__popcll(msk[j] & lt);
            buckets[sv * Nn + off] = gbase + j;
        }
    } else {
        // weight convert: fp32 [D][H] -> bf16 fragment-linear for 12 live matrices
        int u = (blockIdx.x - 64) * 256 + tid;      // 0..24575
        int mat = u >> 11;
        int rr = u & 2047;
        int f = rr >> 6, lane = rr & 63;
        int kk = f >> 3, n8 = f & 7;
        int q = lane >> 4, l15 = lane & 15;
        int sm = mat / 3, w = mat - sm * 3;
        int t = best_t_for(tm, sm, nullptr);
        const float* src = (w == 0) ? W1 : (w == 1) ? W2 : C1;
        const float* sp = src + (((sm * 4 + t) << 14) + n8 * 16 + l15);
        int k0 = kk * 32 + q * 8;
        s16x8 o;
#pragma unroll
        for (int j = 0; j < 8; ++j) o[j] = (short)f2bf(sp[(k0 + j) * 128]);
        *(s16x8*)(wbf + (size_t)u * 8) = o;
    }
}

// ================= k_main: 8-wave blocks, 16 cols/wave, low register demand =================
// (unchanged from round 3 except countsPad indexing — it dropped below the 43us fill in the
// profile, i.e. <=43us; frozen this round while k_prep is fixed)
// A/H layout: row*128 + ((col + (row&15)*8) & 127)  -- pad-free, conflict-free b128 frags
__global__ __launch_bounds__(512, 4) void k_main(
    const float* __restrict__ states, const float* __restrict__ scores,
    const float* __restrict__ b1g, const float* __restrict__ b2g, const float* __restrict__ c1g,
    const float* __restrict__ tm, const float* __restrict__ C2, const float* __restrict__ c2,
    const int* __restrict__ countsPad, const int* __restrict__ buckets,
    const unsigned short* __restrict__ wbf,
    float* __restrict__ out_state, float* __restrict__ out_score)
{
    __shared__ __align__(16) unsigned short Abuf[64 * 128];   // 16 KB
    __shared__ __align__(16) unsigned short Hbuf[64 * 128];   // 16 KB
    __shared__ int gIdxLds[64];
    __shared__ float scoreLds[64];
    __shared__ float pLds[8][64];                             // 2 KB

    const int s = blockIdx.y;
    const int cnt = countsPad[s * 64];
    const int ntiles = (cnt + 63) >> 6;
    const int bx = blockIdx.x;
    if (bx >= ntiles) return;
    const int t = threadIdx.x;
    const int tt = best_t_for(tm, s, nullptr);
    const int stIdx = s * 4 + tt;

    const int lane = t & 63;
    const int wv = t >> 6;           // wave 0..7 -> 16-col slice
    const int l15 = lane & 15;
    const int quad = lane >> 4;
    const int myRow = t >> 3;        // A staging: 8 threads per row
    const int q8 = t & 7;
    const int col = wv * 16 + l15;   // this lane's output column

    // per-lane bias/weight constants (single column per lane)
    const float b1v = b1g[stIdx * 128 + col];
    const float b2v = b2g[stIdx * 128 + col];
    const float c1v = c1g[stIdx * 128 + col];
    const float c2w = C2[stIdx * 128 + col];
    const float c2s = c2[stIdx];
    const int* bkt = buckets + s * Nn;
    const unsigned short* wb = wbf + (size_t)s * 3 * 16384;

    // all 3 matrices' fragments for this wave's 16-col slice: 3*4*4 = 48 VGPRs, loaded once
    s16x8 wf[3][4];
#pragma unroll
    for (int m = 0; m < 3; ++m)
#pragma unroll
        for (int kk = 0; kk < 4; ++kk)
            wf[m][kk] = *(const s16x8*)(wb + m * 16384 +
                (size_t)((kk * 8 + wv) * 64 + lane) * 8);

    // gemm: A-frags from swizzled LDS, B-frags from registers (one 16-col slice)
    auto gemm = [&](const unsigned short* Ab, const s16x8 (&wfm)[4], f32x4 acc[4]) {
#pragma unroll
        for (int mg = 0; mg < 4; ++mg) acc[mg] = f32x4{0.f, 0.f, 0.f, 0.f};
#pragma unroll
        for (int kk = 0; kk < 4; ++kk) {
            const int colsw = (kk * 32 + quad * 8 + l15 * 8) & 127;  // row&15 == l15
            s16x8 af[4];
#pragma unroll
            for (int mg = 0; mg < 4; ++mg)
                af[mg] = *(const s16x8*)(Ab + (mg * 16 + l15) * 128 + colsw);
#pragma unroll
            for (int mg = 0; mg < 4; ++mg)
                acc[mg] = __builtin_amdgcn_mfma_f32_16x16x32_bf16(
                    af[mg], wfm[kk], acc[mg], 0, 0, 0);
        }
    };

    f32x4 acc[4];
    for (int tile = bx; tile < ntiles; tile += gridDim.x) {
        if (tile != bx) __syncthreads();   // protect LDS from previous iteration's readers

        // ---- stage tile's A rows -> swizzled bf16 LDS (8 threads/row, 16 elems each) ----
        {
            int gr = tile * 64 + myRow;
            int g = (gr < cnt) ? bkt[gr] : -1;
            if (q8 == 0) {
                gIdxLds[myRow] = g;
                scoreLds[myRow] = (g >= 0) ? scores[g] : 0.f;
            }
            unsigned short* dstRow = &Abuf[myRow * 128];
            const int rot = (myRow & 15) << 3;
            if (g >= 0) {
                const float4* sp = (const float4*)(states + (size_t)g * 128 + q8 * 16);
                float4 v[4];
#pragma unroll
                for (int i = 0; i < 4; ++i) v[i] = sp[i];
#pragma unroll
                for (int i = 0; i < 4; ++i) {
                    int c = (q8 * 16 + i * 4 + rot) & 127;
                    ushort4 o;
                    o.x = f2bf(v[i].x); o.y = f2bf(v[i].y);
                    o.z = f2bf(v[i].z); o.w = f2bf(v[i].w);
                    *(ushort4*)(dstRow + c) = o;
                }
            } else {
#pragma unroll
                for (int i = 0; i < 4; ++i) {
                    int c = (q8 * 16 + i * 4 + rot) & 127;
                    *(ushort4*)(dstRow + c) = ushort4{0, 0, 0, 0};
                }
            }
        }
        __syncthreads();

        // ---- phase 1: h = relu(A@W1 + b1) -> Hbuf (swizzled) ----
        gemm(Abuf, wf[0], acc);
#pragma unroll
        for (int mg = 0; mg < 4; ++mg)
#pragma unroll
            for (int r = 0; r < 4; ++r) {
                int row = mg * 16 + quad * 4 + r;
                float v = fmaxf(acc[mg][r] + b1v, 0.f);
                Hbuf[row * 128 + ((col + ((row & 15) << 3)) & 127)] = f2bf(v);
            }
        __syncthreads();

        // ---- phase 2: y = h@W2 + b2 -> scatter out_state ----
        gemm(Hbuf, wf[1], acc);
#pragma unroll
        for (int mg = 0; mg < 4; ++mg) {
            int gr4[4];
#pragma unroll
            for (int r = 0; r < 4; ++r) gr4[r] = gIdxLds[mg * 16 + quad * 4 + r];
#pragma unroll
            for (int r = 0; r < 4; ++r)
                if (gr4[r] >= 0) out_state[(size_t)gr4[r] * 128 + col] = acc[mg][r] + b2v;
        }

        // ---- phase 3: classifier partials (this wave's 16 cols) ----
        gemm(Abuf, wf[2], acc);
        {
            float part[4][4];
#pragma unroll
            for (int mg = 0; mg < 4; ++mg)
#pragma unroll
                for (int r = 0; r < 4; ++r)
                    part[mg][r] = fmaxf(acc[mg][r] + c1v, 0.f) * c2w;
#pragma unroll
            for (int off = 1; off < 16; off <<= 1)
#pragma unroll
                for (int mg = 0; mg < 4; ++mg)
#pragma unroll
                    for (int r = 0; r < 4; ++r)
                        part[mg][r] += __shfl_xor(part[mg][r], off, 64);
            if (l15 == 0) {
#pragma unroll
                for (int mg = 0; mg < 4; ++mg)
#pragma unroll
                    for (int r = 0; r < 4; ++r)
                        pLds[wv][mg * 16 + quad * 4 + r] = part[mg][r];
            }
        }
        __syncthreads();

        // ---- epilogue: cross-wave sum, sigmoid, min, store (first 64 lanes) ----
        if (t < 64) {
            int eg = gIdxLds[t];
            if (eg >= 0) {
                float tot = pLds[0][t] + pLds[1][t] + pLds[2][t] + pLds[3][t]
                          + pLds[4][t] + pLds[5][t] + pLds[6][t] + pLds[7][t] + c2s;
                float cls = 1.f / (1.f + expf(-tot));
                out_score[eg] = fminf(scoreLds[t], cls);
            }
        }
    }
}

extern "C" void kernel_launch(void* const* d_in, const int* in_sizes, int n_in,
                              void* d_out, int out_size, void* d_ws, size_t ws_size,
                              hipStream_t stream) {
    const float* states = (const float*)d_in[0];
    const float* scores = (const float*)d_in[1];
    const int*   type_ids = (const int*)d_in[2];
    const float* tm = (const float*)d_in[3];
    const float* W1 = (const float*)d_in[4];
    const float* b1 = (const float*)d_in[5];
    const float* W2 = (const float*)d_in[6];
    const float* b2 = (const float*)d_in[7];
    const float* C1 = (const float*)d_in[8];
    const float* c1 = (const float*)d_in[9];
    const float* C2 = (const float*)d_in[10];
    const float* c2 = (const float*)d_in[11];

    char* ws = (char*)d_ws;
    int*   countsPad = (int*)(ws + 0);                      // 4 counters, 256B apart (poisoned)
    int*   buckets = (int*)(ws + 4096);                     // 4 * 65536 ints = 1 MB
    unsigned short* wbf = (unsigned short*)(ws + 1052672);  // 12 * 16384 bf16, frag-linear

    float* out_state = (float*)d_out;                       // N*128
    float* out_score = out_state + (size_t)Nn * 128;        // N
    float* out_prob  = out_score + Nn;                      // N

    k_prep<<<160, 256, 0, stream>>>(type_ids, tm, W1, W2, C1, countsPad, buckets, wbf, out_prob);
    k_main<<<dim3(128, 4), 512, 0, stream>>>(states, scores, b1, b2, c1,
        tm, C2, c2, countsPad, buckets, wbf, out_state, out_score);
}